// Round 3
// baseline (262.247 us; speedup 1.0000x reference)
//
#include <hip/hip_runtime.h>

// Problem constants (from reference): B=8192, M=16, DICT=64, N=8.
#define B_TOTAL 8192
#define M_DIM   16
#define DICT_N  64
#define N_DIM   8

// 1/k table for the Taylor recurrence v_k = (A v_{k-1}) / k (wave-uniform k).
__constant__ float c_invk[34] = {
    0.0f,
    1.0f,        1.0f/2.0f,  1.0f/3.0f,  1.0f/4.0f,
    1.0f/5.0f,   1.0f/6.0f,  1.0f/7.0f,  1.0f/8.0f,
    1.0f/9.0f,   1.0f/10.0f, 1.0f/11.0f, 1.0f/12.0f,
    1.0f/13.0f,  1.0f/14.0f, 1.0f/15.0f, 1.0f/16.0f,
    1.0f/17.0f,  1.0f/18.0f, 1.0f/19.0f, 1.0f/20.0f,
    1.0f/21.0f,  1.0f/22.0f, 1.0f/23.0f, 1.0f/24.0f,
    1.0f/25.0f,  1.0f/26.0f, 1.0f/27.0f, 1.0f/28.0f,
    1.0f/29.0f,  1.0f/30.0f, 1.0f/31.0f, 1.0f/32.0f, 1.0f/33.0f
};

// One thread per (b, s): A = sum_m c[b,m]*psi[m,s] (8x8 in registers, static
// indexing), then out = expm(A) @ x via Taylor-on-vector.
//
// Block = 256 threads = 4 waves. Wave w of block q handles s = 4*(q&15)+w
// for 64 consecutive b's: s is wave-uniform (psi -> s_load, SGPR FMA
// operands), and the block's 4 s-values cover a contiguous 128B span of
// each x/out row -> full L2-line utilization, no write-allocate refetch.
//
// amdgpu_waves_per_eu(4): pin the allocator at the 512/4 = 128-VGPR point
// so the ~94-reg live set stays in arch VGPRs (R2 showed the default
// choice parks A in AGPRs: VGPR_Count=52, 2.4 waves/SIMD, 27% VALUBusy).
__global__
__attribute__((amdgpu_flat_work_group_size(256, 256)))
__attribute__((amdgpu_waves_per_eu(4)))
void transop_expm_kernel(const float* __restrict__ x,
                         const float* __restrict__ c,
                         const float* __restrict__ psi,
                         float* __restrict__ out)
{
    const int q    = blockIdx.x & 15;          // s-quad index (0..15)
    const int bg   = blockIdx.x >> 4;          // b-group (0..127)
    const int wave = threadIdx.x >> 6;         // 0..3, wave-uniform
    const int lane = threadIdx.x & 63;

    const int s = q * 4 + wave;                // wave-uniform dict slot
    const int b = bg * 64 + lane;              // per-lane batch index

    // ---- Build A[n,k] = sum_m c[b,m] * psi[m, s, n, k] ----
    // m processed in 4 chunks of 4 so only 4 c-values are live at a time.
    float A[64];
#pragma unroll
    for (int i = 0; i < 64; ++i) A[i] = 0.0f;

    const float* ps  = psi + (size_t)s * 64;                 // uniform base
    const float4* cb4 = reinterpret_cast<const float4*>(c + (size_t)b * M_DIM);

#pragma unroll
    for (int mq = 0; mq < 4; ++mq) {
        const float4 cv = cb4[mq];                           // c[b, 4mq..+4)
        const float cm[4] = { cv.x, cv.y, cv.z, cv.w };
#pragma unroll
        for (int mm = 0; mm < 4; ++mm) {
            const float* pm = ps + (size_t)(mq * 4 + mm) * (DICT_N * 64);
#pragma unroll
            for (int i = 0; i < 64; ++i)
                A[i] = fmaf(cm[mm], pm[i], A[i]);            // v_fma, SGPR psi
        }
    }

    // ---- Load x block: v = x[b, s*8 .. +8) ----
    const float* xb = x + (size_t)b * (DICT_N * N_DIM) + s * N_DIM;
    float v[8], o[8];
    {
        const float4 t0 = reinterpret_cast<const float4*>(xb)[0];
        const float4 t1 = reinterpret_cast<const float4*>(xb)[1];
        v[0] = t0.x; v[1] = t0.y; v[2] = t0.z; v[3] = t0.w;
        v[4] = t1.x; v[5] = t1.y; v[6] = t1.z; v[7] = t1.w;
    }
#pragma unroll
    for (int i = 0; i < 8; ++i) o[i] = v[i];                 // k=0 term

    // ---- Taylor: o = sum_k A^k x / k!, unrolled x2, j-outer matvec ----
#pragma unroll 1
    for (int k = 1; k <= 31; k += 2) {
        const float inva = c_invk[k];                        // uniform s_load
        const float invb = c_invk[k + 1];

        float t[8];
#pragma unroll
        for (int i = 0; i < 8; ++i) t[i] = A[i * 8] * v[0];  // j = 0
#pragma unroll
        for (int j = 1; j < 8; ++j)                          // 8-wide ILP
#pragma unroll
            for (int i = 0; i < 8; ++i)
                t[i] = fmaf(A[i * 8 + j], v[j], t[i]);
#pragma unroll
        for (int i = 0; i < 8; ++i) { t[i] *= inva; o[i] += t[i]; }

        float u[8];
#pragma unroll
        for (int i = 0; i < 8; ++i) u[i] = A[i * 8] * t[0];
#pragma unroll
        for (int j = 1; j < 8; ++j)
#pragma unroll
            for (int i = 0; i < 8; ++i)
                u[i] = fmaf(A[i * 8 + j], t[j], u[i]);
#pragma unroll
        for (int i = 0; i < 8; ++i) {
            u[i] *= invb;
            o[i] += u[i];
            v[i] = u[i];
        }

        // |next terms| bounded by ~mx once shrinking; 2e-4 adds <=1e-3 abs
        // error vs the 1.56 threshold (R2 margin: 0.0625). Tree-max.
        const float m01 = fmaxf(fabsf(u[0]), fabsf(u[1]));
        const float m23 = fmaxf(fabsf(u[2]), fabsf(u[3]));
        const float m45 = fmaxf(fabsf(u[4]), fabsf(u[5]));
        const float m67 = fmaxf(fabsf(u[6]), fabsf(u[7]));
        const float mx  = fmaxf(fmaxf(m01, m23), fmaxf(m45, m67));
        if (__all(mx < 2e-4f)) break;
    }

    // ---- Store out[b, s*8 .. +8) ----
    float* ob = out + (size_t)b * (DICT_N * N_DIM) + s * N_DIM;
    float4 r0, r1;
    r0.x = o[0]; r0.y = o[1]; r0.z = o[2]; r0.w = o[3];
    r1.x = o[4]; r1.y = o[5]; r1.z = o[6]; r1.w = o[7];
    reinterpret_cast<float4*>(ob)[0] = r0;
    reinterpret_cast<float4*>(ob)[1] = r1;
}

extern "C" void kernel_launch(void* const* d_in, const int* in_sizes, int n_in,
                              void* d_out, int out_size, void* d_ws, size_t ws_size,
                              hipStream_t stream)
{
    const float* x   = (const float*)d_in[0];  // (8192, 512)
    const float* c   = (const float*)d_in[1];  // (8192, 16)
    const float* psi = (const float*)d_in[2];  // (16, 64, 8, 8)
    float* out = (float*)d_out;                // (8192, 512)

    // 16 s-quads * 128 b-groups = 2048 blocks of 256 threads.
    dim3 grid(16 * (B_TOTAL / 64));
    dim3 block(256);
    hipLaunchKernelGGL(transop_expm_kernel, grid, block, 0, stream,
                       x, c, psi, out);
}

// Round 4
// 138.643 us; speedup vs baseline: 1.8915x; 1.8915x over previous
//
#include <hip/hip_runtime.h>

// Problem constants (from reference): B=8192, M=16, DICT=64, N=8.
#define B_TOTAL 8192
#define M_DIM   16
#define DICT_N  64
#define N_DIM   8

// 1/k table for the Taylor recurrence v_k = (A v_{k-1}) / k.
__constant__ float c_invk[34] = {
    0.0f,
    1.0f,        1.0f/2.0f,  1.0f/3.0f,  1.0f/4.0f,
    1.0f/5.0f,   1.0f/6.0f,  1.0f/7.0f,  1.0f/8.0f,
    1.0f/9.0f,   1.0f/10.0f, 1.0f/11.0f, 1.0f/12.0f,
    1.0f/13.0f,  1.0f/14.0f, 1.0f/15.0f, 1.0f/16.0f,
    1.0f/17.0f,  1.0f/18.0f, 1.0f/19.0f, 1.0f/20.0f,
    1.0f/21.0f,  1.0f/22.0f, 1.0f/23.0f, 1.0f/24.0f,
    1.0f/25.0f,  1.0f/26.0f, 1.0f/27.0f, 1.0f/28.0f,
    1.0f/29.0f,  1.0f/30.0f, 1.0f/31.0f, 1.0f/32.0f, 1.0f/33.0f
};

// 8 lanes per (b,s) matrix: lane owns ROW r of A (8 regs). Wave = 8 b's x
// one s; block = 4 waves covering s..s+3 for the same 8 b's (full 128B
// line spans on x/out). psi is read via small per-lane VMEM loads (L2-hot,
// 256KB total) -- no SGPR scalarity needed, so per-wave s is safe (R3's
// failure was per-wave s COMBINED with the SGPR-psi design).
//
// Taylor step: t_r = dot(A_row, v) * 1/k; v is replicated per thread and
// refreshed each step by an 8-lane allgather through LDS (1 ds_write_b32 +
// 2 ds_read_b128, disjoint 256B region per wave -> no barrier needed,
// wave-lockstep ordering + compiler lgkmcnt handle the dependence).
//
// Live set ~45 VGPRs -> __launch_bounds__(256, 8) = 64-VGPR cap,
// 8 waves/SIMD: latency (psi VMEM, LDS round-trip, FMA chains) hidden by
// TLP instead of fought with registers (R2 was 2.4 waves/SIMD, 73% stall).
__global__ __launch_bounds__(256, 8)
void transop_expm_kernel(const float* __restrict__ x,
                         const float* __restrict__ c,
                         const float* __restrict__ psi,
                         float* __restrict__ out)
{
    __shared__ float red[256];   // 1KB: 64B allgather slab per wave

    const int tid  = threadIdx.x;
    const int wave = tid >> 6;                 // 0..3
    const int lane = tid & 63;
    const int bl   = lane >> 3;                // b within group-of-8
    const int r    = lane & 7;                 // owned matrix row

    const int q  = blockIdx.x & 15;            // s-quad
    const int bg = blockIdx.x >> 4;            // 0..1023
    const int s  = q * 4 + wave;               // per-wave dict slot
    const int b  = bg * 8 + bl;                // batch index

    // ---- A row: Ar[j] = sum_m c[b,m] * psi[m, s, r, j] ----
    // psi[m,s,r,j] flat = m*4096 + s*64 + r*8 + j.
    float Ar[8];
#pragma unroll
    for (int j = 0; j < 8; ++j) Ar[j] = 0.0f;

    const float* psr = psi + (size_t)s * (N_DIM * N_DIM) + (size_t)r * N_DIM;
    const float4* cb4 = reinterpret_cast<const float4*>(c + (size_t)b * M_DIM);

#pragma unroll
    for (int mq = 0; mq < 4; ++mq) {
        const float4 cv = cb4[mq];             // c[b, 4mq..+4) (8-lane bcast)
        const float cmv[4] = { cv.x, cv.y, cv.z, cv.w };
#pragma unroll
        for (int mm = 0; mm < 4; ++mm) {
            const float4* pr = reinterpret_cast<const float4*>(
                psr + (size_t)(mq * 4 + mm) * (DICT_N * N_DIM * N_DIM));
            const float4 p0 = pr[0];
            const float4 p1 = pr[1];
            const float cm = cmv[mm];          // constant idx after unroll
            Ar[0] = fmaf(cm, p0.x, Ar[0]);
            Ar[1] = fmaf(cm, p0.y, Ar[1]);
            Ar[2] = fmaf(cm, p0.z, Ar[2]);
            Ar[3] = fmaf(cm, p0.w, Ar[3]);
            Ar[4] = fmaf(cm, p1.x, Ar[4]);
            Ar[5] = fmaf(cm, p1.y, Ar[5]);
            Ar[6] = fmaf(cm, p1.z, Ar[6]);
            Ar[7] = fmaf(cm, p1.w, Ar[7]);
        }
    }

    // ---- v = x[b, s*8 .. +8) replicated; o = own element (k=0 term) ----
    const float* xb = x + (size_t)b * (DICT_N * N_DIM) + (size_t)s * N_DIM;
    const float4 x0 = reinterpret_cast<const float4*>(xb)[0];
    const float4 x1 = reinterpret_cast<const float4*>(xb)[1];
    float v[8] = { x0.x, x0.y, x0.z, x0.w, x1.x, x1.y, x1.z, x1.w };
    float o = xb[r];   // scalar load: avoids runtime-indexing v[r] (rule #20)

    float* myred = &red[tid];
    const float4* grp = reinterpret_cast<const float4*>(&red[tid & ~7]);

    // ---- Taylor: o = sum_k (A^k x / k!)[r], two steps per trip ----
#pragma unroll 1
    for (int k = 1; k <= 31; k += 2) {
        float t = Ar[0] * v[0];
#pragma unroll
        for (int j = 1; j < 8; ++j) t = fmaf(Ar[j], v[j], t);
        t *= c_invk[k];
        o += t;

        // allgather t across the 8-lane group -> new replicated v
        *myred = t;
        {
            const float4 g0 = grp[0];
            const float4 g1 = grp[1];
            v[0] = g0.x; v[1] = g0.y; v[2] = g0.z; v[3] = g0.w;
            v[4] = g1.x; v[5] = g1.y; v[6] = g1.z; v[7] = g1.w;
        }

        float u = Ar[0] * v[0];
#pragma unroll
        for (int j = 1; j < 8; ++j) u = fmaf(Ar[j], v[j], u);
        u *= c_invk[k + 1];
        o += u;

        // All rows of all 8 matrices in this wave below threshold ->
        // remaining tail < ~2e-4; adds <=1e-3 abs error vs 1.56 threshold
        // (R2 margin was 0.0625). Break BEFORE redistributing (v unneeded).
        if (__all(fabsf(u) < 2e-4f)) break;

        *myred = u;
        {
            const float4 g0 = grp[0];
            const float4 g1 = grp[1];
            v[0] = g0.x; v[1] = g0.y; v[2] = g0.z; v[3] = g0.w;
            v[4] = g1.x; v[5] = g1.y; v[6] = g1.z; v[7] = g1.w;
        }
    }

    // ---- Store own output element (32B contiguous per 8-lane group) ----
    out[(size_t)b * (DICT_N * N_DIM) + (size_t)s * N_DIM + r] = o;
}

extern "C" void kernel_launch(void* const* d_in, const int* in_sizes, int n_in,
                              void* d_out, int out_size, void* d_ws, size_t ws_size,
                              hipStream_t stream)
{
    const float* x   = (const float*)d_in[0];  // (8192, 512)
    const float* c   = (const float*)d_in[1];  // (8192, 16)
    const float* psi = (const float*)d_in[2];  // (16, 64, 8, 8)
    float* out = (float*)d_out;                // (8192, 512)

    // 16 s-quads * 1024 b-groups = 16384 blocks of 256 threads
    // (8 threads per (b,s) matrix, 32 matrices per block).
    dim3 grid(16 * (B_TOTAL / 8));
    dim3 block(256);
    hipLaunchKernelGGL(transop_expm_kernel, grid, block, 0, stream,
                       x, c, psi, out);
}